// Round 5
// baseline (2126.027 us; speedup 1.0000x reference)
//
#include <hip/hip_runtime.h>
#include <math.h>

#define Bz   4096
#define Tz   200
#define Fz   18
#define Uz   128
#define NIDS 1000
#define NCH  4
#define NWG  250   // NIDS/NCH

__device__ __forceinline__ float hsig(float x) {
    return fminf(fmaxf(fmaf(x, 0.2f, 0.5f), 0.0f), 1.0f);
}
__device__ __forceinline__ float rlane(float v, int l) {
    return __int_as_float(__builtin_amdgcn_readlane(__float_as_int(v), l));
}

// ---------------------------------------------------------------------------
// K1: winner per (t,id): win[t*NIDS+id] = max{b : ids[b,t]==id}  (last-wins)
// ---------------------------------------------------------------------------
__global__ void k_winner(const float* __restrict__ in, int* __restrict__ win) {
    int idx = blockIdx.x * blockDim.x + threadIdx.x;
    if (idx >= Bz * Tz) return;
    int b = idx / Tz, t = idx - b * Tz;
    int id = (int)in[(size_t)idx * Fz];
    id = min(max(id, 0), NIDS - 1);
    atomicMax(&win[t * NIDS + id], b);
}

// ---------------------------------------------------------------------------
// One GRU step, 1024 threads = 16 waves, 4 chains (j-packed float4 LDS).
// stage1 (256 cols): wave-pair p=w>>1 owns k in [16p,16p+16); half hw=w&1
//   covers cols {hw*128+lane, +64}. Partials -> pbuf[8][256] (float4 chains).
// stage2 (128 cols): wave w owns k in [8w,8w+8); cols {lane, lane+64}.
//   Partials -> pbuf[16][128] (reuses same 32 KB buffer).
// Reductions spread across all threads: pbuff[pp*1024+tid] (conflict-free).
// ---------------------------------------------------------------------------
template<bool MASK>
__device__ __forceinline__ void gstep(
    int tid, int w, int p, int hw, int lane, int l15, int l7,
    const float (&wzr)[16][2], const float (&wh)[8][2],
    const float (&wk1)[3][2], const float (&wk2)[2][2],
    int f0, int f1, int f2, int g0, int g1,
    float breg1, float breg2,
    float* hldsf, float* ubuff, float* zbuff, float4* pbuf, float* pbuff,
    float xa, float xb, int4 act)
{
    // ---- stage 1: partials of [x@K + h@Rzr] over (k-slice 16, col-half) ----
    float4 hd4 = ((const float4*)hldsf)[p * 16 + l15];
    float hdj[4] = {hd4.x, hd4.y, hd4.z, hd4.w};
    float az[2][4];
#pragma unroll
    for (int j = 0; j < 4; ++j) { az[0][j] = 0.f; az[1][j] = 0.f; }

#pragma unroll
    for (int j = 0; j < 4; ++j) {
        float src = (j < 2) ? xa : xb;
        int base = (j & 1) * 18;
        float xv0 = rlane(src, base + f0);
        float xv1 = rlane(src, base + f1);
        float xv2 = rlane(src, base + f2);
        az[0][j] = fmaf(xv0, wk1[0][0], az[0][j]);
        az[1][j] = fmaf(xv0, wk1[0][1], az[1][j]);
        az[0][j] = fmaf(xv1, wk1[1][0], az[0][j]);
        az[1][j] = fmaf(xv1, wk1[1][1], az[1][j]);
        az[0][j] = fmaf(xv2, wk1[2][0], az[0][j]);
        az[1][j] = fmaf(xv2, wk1[2][1], az[1][j]);
    }
#pragma unroll
    for (int kl = 0; kl < 16; ++kl) {
#pragma unroll
        for (int j = 0; j < 4; ++j) {
            float hv = rlane(hdj[j], kl);
            az[0][j] = fmaf(hv, wzr[kl][0], az[0][j]);
            az[1][j] = fmaf(hv, wzr[kl][1], az[1][j]);
        }
    }
    pbuf[p * 256 + hw * 128 + lane]      = make_float4(az[0][0], az[0][1], az[0][2], az[0][3]);
    pbuf[p * 256 + hw * 128 + lane + 64] = make_float4(az[1][0], az[1][1], az[1][2], az[1][3]);
    __syncthreads();                                   // A

    // ---- reduce1 (all 1024 threads; c = tid>>2, j = tid&3) ----
    {
        float s = breg1;
#pragma unroll
        for (int pp = 0; pp < 8; ++pp) s += pbuff[pp * 1024 + tid];
        if (tid < 512) {
            zbuff[tid] = hsig(s);
        } else {
            int cu = tid - 512;
            ubuff[cu] = hsig(s) * hldsf[cu];
        }
    }
    __syncthreads();                                   // B

    // ---- stage 2: partials of [x@K2 + u@Rh] over (k-slice 8, M=2 cols) ----
    float4 ud4 = ((const float4*)ubuff)[w * 8 + l7];
    float udj[4] = {ud4.x, ud4.y, ud4.z, ud4.w};
    float pa[2][4];
#pragma unroll
    for (int j = 0; j < 4; ++j) { pa[0][j] = 0.f; pa[1][j] = 0.f; }
#pragma unroll
    for (int j = 0; j < 4; ++j) {
        float src = (j < 2) ? xa : xb;
        int base = (j & 1) * 18;
        float xv0 = rlane(src, base + g0);
        float xv1 = rlane(src, base + g1);
        pa[0][j] = fmaf(xv0, wk2[0][0], pa[0][j]);
        pa[1][j] = fmaf(xv0, wk2[0][1], pa[1][j]);
        pa[0][j] = fmaf(xv1, wk2[1][0], pa[0][j]);
        pa[1][j] = fmaf(xv1, wk2[1][1], pa[1][j]);
    }
#pragma unroll
    for (int kl = 0; kl < 8; ++kl) {
#pragma unroll
        for (int j = 0; j < 4; ++j) {
            float uv = rlane(udj[j], kl);
            pa[0][j] = fmaf(uv, wh[kl][0], pa[0][j]);
            pa[1][j] = fmaf(uv, wh[kl][1], pa[1][j]);
        }
    }
    pbuf[w * 128 + lane]      = make_float4(pa[0][0], pa[0][1], pa[0][2], pa[0][3]);
    pbuf[w * 128 + lane + 64] = make_float4(pa[1][0], pa[1][1], pa[1][2], pa[1][3]);
    __syncthreads();                                   // C

    // ---- reduce2 + finish (tid < 512): h_new -> hlds ----
    if (tid < 512) {
        float s = breg2;
#pragma unroll
        for (int ww = 0; ww < 16; ++ww) s += pbuff[ww * 512 + tid];
        float hh = tanhf(s);
        float z  = zbuff[tid];
        float ho = hldsf[tid];
        float hn = fmaf(z, ho - hh, hh);
        if (MASK) {
            int j = tid & 3;
            int av = (j == 0) ? act.x : (j == 1) ? act.y : (j == 2) ? act.z : act.w;
            if (av < 0) hn = ho;
        }
        hldsf[tid] = hn;
    }
    __syncthreads();                                   // D
}

// ---------------------------------------------------------------------------
// weight preload (58 floats/thread) shared by both kernels
// ---------------------------------------------------------------------------
#define LOAD_WEIGHTS                                                          \
    float wzr[16][2], wh[8][2], wk1[3][2], wk2[2][2];                         \
    _Pragma("unroll")                                                         \
    for (int kl = 0; kl < 16; ++kl) {                                         \
        int row = (p * 16 + kl) * 384 + hw * 128 + lane;                      \
        wzr[kl][0] = rk[row];                                                 \
        wzr[kl][1] = rk[row + 64];                                            \
    }                                                                         \
    _Pragma("unroll")                                                         \
    for (int kl = 0; kl < 8; ++kl) {                                          \
        int row = (w * 8 + kl) * 384 + 256 + lane;                            \
        wh[kl][0] = rk[row];                                                  \
        wh[kl][1] = rk[row + 64];                                             \
    }                                                                         \
    int f0 = 2 * p, f1 = 2 * p + 1, f2 = (p < 2) ? 16 + p : 0;                \
    {                                                                         \
        int r0 = f0 * 384 + hw * 128 + lane;                                  \
        int r1 = f1 * 384 + hw * 128 + lane;                                  \
        int r2 = f2 * 384 + hw * 128 + lane;                                  \
        wk1[0][0] = ker[r0];  wk1[0][1] = ker[r0 + 64];                       \
        wk1[1][0] = ker[r1];  wk1[1][1] = ker[r1 + 64];                       \
        wk1[2][0] = (p < 2) ? ker[r2] : 0.0f;                                 \
        wk1[2][1] = (p < 2) ? ker[r2 + 64] : 0.0f;                            \
    }                                                                         \
    int g0 = w, g1 = (w < 2) ? 16 + w : 0;                                    \
    {                                                                         \
        int r0 = g0 * 384 + 256 + lane;                                       \
        int r1 = g1 * 384 + 256 + lane;                                       \
        wk2[0][0] = ker[r0];  wk2[0][1] = ker[r0 + 64];                       \
        wk2[1][0] = (w < 2) ? ker[r1] : 0.0f;                                 \
        wk2[1][1] = (w < 2) ? ker[r1 + 64] : 0.0f;                            \
    }                                                                         \
    float breg1 = bias[tid >> 2];                                             \
    float breg2 = (tid < 512) ? bias[256 + (tid >> 2)] : 0.0f;

#define DECLARE_IDX                                                           \
    const int tid  = threadIdx.x;                                             \
    const int w    = tid >> 6;                                                \
    const int lane = tid & 63;                                                \
    const int p    = w >> 1;                                                  \
    const int hw   = w & 1;                                                   \
    const int l15  = lane & 15;                                               \
    const int l7   = lane & 7;

#define DECLARE_LDS                                                           \
    __shared__ __align__(16) float4 hlds4[Uz], ubuf4[Uz], zbuf4[Uz];          \
    __shared__ __align__(16) float4 pbuf[2048]; /* 32 KB, stage1+2 union */   \
    float* hldsf = (float*)hlds4;                                             \
    float* ubuff = (float*)ubuf4;                                             \
    float* zbuff = (float*)zbuf4;                                             \
    float* pbuff = (float*)pbuf;

// ---------------------------------------------------------------------------
// K2: 250 wgs x 1024 threads; 4 chains/wg; t = 0..198
// ---------------------------------------------------------------------------
__global__ __launch_bounds__(1024, 4)
void k_scan(const float* __restrict__ in,  const float* __restrict__ ker,
            const float* __restrict__ rk,  const float* __restrict__ bias,
            const float* __restrict__ sh0, const int* __restrict__ win,
            float* __restrict__ sfinal)
{
    DECLARE_IDX
    const int bx = blockIdx.x;
    DECLARE_LDS
    LOAD_WEIGHTS

    if (tid < 512)
        hldsf[tid] = sh0[(bx * 4 + (tid & 3)) * Uz + (tid >> 2)];

    const int4* winp = (const int4*)win;               // [Tz][NWG]
    int4 wv_cur = winp[bx];
    int4 wv_nxt = winp[NWG + bx];

    auto ldx = [&](int4 wv, int t, int jb) -> float {
        if (lane >= 36) return 0.0f;
        int j = lane / 18, f = lane - j * 18;
        int jj = jb + j;
        int b = (jj == 0) ? wv.x : (jj == 1) ? wv.y : (jj == 2) ? wv.z : wv.w;
        if (b < 0) return 0.0f;
        return in[((size_t)b * Tz + t) * Fz + f];
    };
    float xa = ldx(wv_cur, 0, 0), xb = ldx(wv_cur, 0, 2);
    __syncthreads();

    for (int t = 0; t < Tz - 1; ++t) {
        int tf = (t + 2 < Tz) ? t + 2 : Tz - 1;
        int4  wv_fut = winp[tf * NWG + bx];
        float xaN = ldx(wv_nxt, t + 1, 0);             // prefetch x(t+1)
        float xbN = ldx(wv_nxt, t + 1, 2);

        gstep<true>(tid, w, p, hw, lane, l15, l7, wzr, wh, wk1, wk2,
                    f0, f1, f2, g0, g1, breg1, breg2,
                    hldsf, ubuff, zbuff, pbuf, pbuff, xa, xb, wv_cur);

        xa = xaN; xb = xbN; wv_cur = wv_nxt; wv_nxt = wv_fut;
    }

    if (tid < 512) sfinal[bx * 512 + tid] = hldsf[tid];
}

// ---------------------------------------------------------------------------
// K3: final step t=199 for all 4096 rows + fused MLP head
// 256 wgs x 1024 threads, 4 iterations of 4 rows
// ---------------------------------------------------------------------------
__global__ __launch_bounds__(1024, 4)
void k_final(const float* __restrict__ in,  const float* __restrict__ ker,
             const float* __restrict__ rk,  const float* __restrict__ bias,
             const float* __restrict__ sfinal,
             const float* __restrict__ w1,  const float* __restrict__ b1,
             const float* __restrict__ w2,  const float* __restrict__ b2,
             float* __restrict__ out)
{
    DECLARE_IDX
    DECLARE_LDS
    LOAD_WEIGHTS

    for (int it = 0; it < 4; ++it) {
        int bbase = blockIdx.x * 16 + it * 4;

        if (tid < 512) {   // gather h = sfinal[id]; chain j = tid&3, col c = tid>>2
            int j  = tid & 3, c = tid >> 2;
            int id = (int)in[((size_t)(bbase + j) * Tz + (Tz - 1)) * Fz];
            id = min(max(id, 0), NIDS - 1);
            hldsf[tid] = sfinal[((id >> 2) * Uz + c) * 4 + (id & 3)];
        }
        float xa = 0.0f, xb = 0.0f;
        if (lane < 36) {
            int j = lane / 18, f = lane - j * 18;
            xa = in[((size_t)(bbase + j)     * Tz + (Tz - 1)) * Fz + f];
            xb = in[((size_t)(bbase + 2 + j) * Tz + (Tz - 1)) * Fz + f];
        }
        __syncthreads();

        gstep<false>(tid, w, p, hw, lane, l15, l7, wzr, wh, wk1, wk2,
                     f0, f1, f2, g0, g1, breg1, breg2,
                     hldsf, ubuff, zbuff, pbuf, pbuff, xa, xb,
                     make_int4(0, 0, 0, 0));

        // MLP head: wave j = tid>>6 (<4) handles row j; lane = hidden unit
        if (tid < 256) {
            int j  = tid >> 6, un = tid & 63;
            float dacc = b1[un];
#pragma unroll
            for (int k = 0; k < Uz; ++k)
                dacc = fmaf(hldsf[k * 4 + j], w1[k * 64 + un], dacc);
            float v = fmaxf(dacc, 0.0f) * w2[un];
#pragma unroll
            for (int off = 32; off > 0; off >>= 1) v += __shfl_xor(v, off, 64);
            if (un == 0)
                out[bbase + j] = 1.0f / (1.0f + expf(-(v + b2[0])));
        }
        __syncthreads();
    }
}

// ---------------------------------------------------------------------------
extern "C" void kernel_launch(void* const* d_in, const int* in_sizes, int n_in,
                              void* d_out, int out_size, void* d_ws, size_t ws_size,
                              hipStream_t stream) {
    const float* in   = (const float*)d_in[0];
    const float* ker  = (const float*)d_in[1];
    const float* rk   = (const float*)d_in[2];
    const float* bias = (const float*)d_in[3];
    const float* sh0  = (const float*)d_in[4];
    const float* w1   = (const float*)d_in[5];
    const float* b1   = (const float*)d_in[6];
    const float* w2   = (const float*)d_in[7];
    const float* b2   = (const float*)d_in[8];
    float* out = (float*)d_out;

    int*   win    = (int*)d_ws;                                          // [Tz][NIDS]
    float* sfinal = (float*)((char*)d_ws + (size_t)Tz * NIDS * sizeof(int));

    hipMemsetAsync(win, 0xFF, (size_t)Tz * NIDS * sizeof(int), stream);  // -1

    hipLaunchKernelGGL(k_winner, dim3((Bz * Tz + 255) / 256), dim3(256), 0, stream,
                       in, win);
    hipLaunchKernelGGL(k_scan, dim3(NWG), dim3(1024), 0, stream,
                       in, ker, rk, bias, sh0, win, sfinal);
    hipLaunchKernelGGL(k_final, dim3(Bz / 16), dim3(1024), 0, stream,
                       in, ker, rk, bias, sfinal, w1, b1, w2, b2, out);
}

// Round 6
// 1610.649 us; speedup vs baseline: 1.3200x; 1.3200x over previous
//
#include <hip/hip_runtime.h>
#include <math.h>

#define Bz   4096
#define Tz   200
#define Fz   18
#define Uz   128
#define NIDS 1000
#define NWG  250   // NIDS/4

__device__ __forceinline__ float hsig(float x) {
    return fminf(fmaxf(fmaf(x, 0.2f, 0.5f), 0.0f), 1.0f);
}
__device__ __forceinline__ float rlane(float v, int l) {
    return __int_as_float(__builtin_amdgcn_readlane(__float_as_int(v), l));
}

// ---------------------------------------------------------------------------
// K1: winner per (t,id): win[t*NIDS+id] = max{b : ids[b,t]==id}  (last-wins)
// ---------------------------------------------------------------------------
__global__ void k_winner(const float* __restrict__ in, int* __restrict__ win) {
    int idx = blockIdx.x * blockDim.x + threadIdx.x;
    if (idx >= Bz * Tz) return;
    int b = idx / Tz, t = idx - b * Tz;
    int id = (int)in[(size_t)idx * Fz];
    id = min(max(id, 0), NIDS - 1);
    atomicMax(&win[t * NIDS + id], b);
}

// ---------------------------------------------------------------------------
// One GRU step, 1024 threads = 16 waves, 4 chains, 3 barriers.
// stage1 (256 cols): wave-pair p=w>>1 owns k in [16p,16p+16); half hw=w&1
//   covers cols {hw*128+lane, +64}. Partials -> p1f[8][256][4] (32 KB).
// u-reduce: wave w reduces its OWN 8 r-cols (no barrier needed after),
//   u kept in registers (lane uq*4+uj holds u[8w+uq][chain uj]).
// stage2 (128 cols): wave w owns k in [8w,8w+8); cols {lane, lane+64}.
//   Partials -> p2f[16][128][4] (32 KB, separate buffer: p1f stays live
//   because finish still needs the z-columns from it).
// finish (tid<512): z-reduce from p1f + p-reduce from p2f -> h_new.
// ---------------------------------------------------------------------------
template<bool MASK>
__device__ __forceinline__ void gstep(
    int tid, int w, int p, int hw, int lane,
    const float (&wzr)[16][2], const float (&wh)[8][2],
    const float (&wk1)[3][2], const float (&wk2)[2][2],
    int f0, int f1, int f2, int g0, int g1,
    float ubias, float fbz, float fbh,
    float* hldsf, float* p1f, float* p2f,
    float xa, float xb, int4 act)
{
    const int l15 = lane & 15;
    const int l31 = lane & 31;

    // ---- stage 1: partials of [x@K + h@Rzr] over (k-slice 16, col-half) ----
    float4 hd4 = ((const float4*)hldsf)[p * 16 + l15];
    float hdj[4] = {hd4.x, hd4.y, hd4.z, hd4.w};
    float az[2][4];
#pragma unroll
    for (int j = 0; j < 4; ++j) { az[0][j] = 0.f; az[1][j] = 0.f; }

#pragma unroll
    for (int j = 0; j < 4; ++j) {
        float src = (j < 2) ? xa : xb;
        int base = (j & 1) * 18;
        float xv0 = rlane(src, base + f0);
        float xv1 = rlane(src, base + f1);
        float xv2 = rlane(src, base + f2);
        az[0][j] = fmaf(xv0, wk1[0][0], az[0][j]);
        az[1][j] = fmaf(xv0, wk1[0][1], az[1][j]);
        az[0][j] = fmaf(xv1, wk1[1][0], az[0][j]);
        az[1][j] = fmaf(xv1, wk1[1][1], az[1][j]);
        az[0][j] = fmaf(xv2, wk1[2][0], az[0][j]);
        az[1][j] = fmaf(xv2, wk1[2][1], az[1][j]);
    }
#pragma unroll
    for (int kl = 0; kl < 16; ++kl) {
#pragma unroll
        for (int j = 0; j < 4; ++j) {
            float hv = rlane(hdj[j], kl);
            az[0][j] = fmaf(hv, wzr[kl][0], az[0][j]);
            az[1][j] = fmaf(hv, wzr[kl][1], az[1][j]);
        }
    }
    ((float4*)p1f)[p * 256 + hw * 128 + lane]      = make_float4(az[0][0], az[0][1], az[0][2], az[0][3]);
    ((float4*)p1f)[p * 256 + hw * 128 + lane + 64] = make_float4(az[1][0], az[1][1], az[1][2], az[1][3]);
    __syncthreads();                                   // A

    // ---- wave-local u-reduce: u[8w+uq][uj] into lane l31 = uq*4+uj ----
    float ureg;
    {
        int uq = l31 >> 2, uj = l31 & 3;
        int ucol = 128 + 8 * w + uq;
        float us = ubias;
#pragma unroll
        for (int pp = 0; pp < 8; ++pp) us += p1f[pp * 1024 + ucol * 4 + uj];
        ureg = hsig(us) * hldsf[(8 * w + uq) * 4 + uj];
    }

    // ---- stage 2: partials of [x@K2 + u@Rh] over (k-slice 8, M=2 cols) ----
    float pa[2][4];
#pragma unroll
    for (int j = 0; j < 4; ++j) { pa[0][j] = 0.f; pa[1][j] = 0.f; }
#pragma unroll
    for (int j = 0; j < 4; ++j) {
        float src = (j < 2) ? xa : xb;
        int base = (j & 1) * 18;
        float xv0 = rlane(src, base + g0);
        float xv1 = rlane(src, base + g1);
        pa[0][j] = fmaf(xv0, wk2[0][0], pa[0][j]);
        pa[1][j] = fmaf(xv0, wk2[0][1], pa[1][j]);
        pa[0][j] = fmaf(xv1, wk2[1][0], pa[0][j]);
        pa[1][j] = fmaf(xv1, wk2[1][1], pa[1][j]);
    }
#pragma unroll
    for (int kl = 0; kl < 8; ++kl) {
#pragma unroll
        for (int j = 0; j < 4; ++j) {
            float uv = rlane(ureg, kl * 4 + j);
            pa[0][j] = fmaf(uv, wh[kl][0], pa[0][j]);
            pa[1][j] = fmaf(uv, wh[kl][1], pa[1][j]);
        }
    }
    ((float4*)p2f)[w * 128 + lane]      = make_float4(pa[0][0], pa[0][1], pa[0][2], pa[0][3]);
    ((float4*)p2f)[w * 128 + lane + 64] = make_float4(pa[1][0], pa[1][1], pa[1][2], pa[1][3]);
    __syncthreads();                                   // C

    // ---- finish (tid < 512): z-reduce + p-reduce -> h_new -> hlds ----
    if (tid < 512) {
        float zs = fbz;
#pragma unroll
        for (int pp = 0; pp < 8; ++pp) zs += p1f[pp * 1024 + tid];
        float z = hsig(zs);
        float ps = fbh;
#pragma unroll
        for (int ww = 0; ww < 16; ++ww) ps += p2f[ww * 512 + tid];
        float hh = tanhf(ps);
        float ho = hldsf[tid];
        float hn = fmaf(z, ho - hh, hh);
        if (MASK) {
            int j = tid & 3;
            int av = (j == 0) ? act.x : (j == 1) ? act.y : (j == 2) ? act.z : act.w;
            if (av < 0) hn = ho;
        }
        hldsf[tid] = hn;
    }
    __syncthreads();                                   // D
}

// ---------------------------------------------------------------------------
// weight preload (58 floats/thread) + bias regs, shared by both kernels
// ---------------------------------------------------------------------------
#define LOAD_WEIGHTS                                                          \
    float wzr[16][2], wh[8][2], wk1[3][2], wk2[2][2];                         \
    _Pragma("unroll")                                                         \
    for (int kl = 0; kl < 16; ++kl) {                                         \
        int row = (p * 16 + kl) * 384 + hw * 128 + lane;                      \
        wzr[kl][0] = rk[row];                                                 \
        wzr[kl][1] = rk[row + 64];                                            \
    }                                                                         \
    _Pragma("unroll")                                                         \
    for (int kl = 0; kl < 8; ++kl) {                                          \
        int row = (w * 8 + kl) * 384 + 256 + lane;                            \
        wh[kl][0] = rk[row];                                                  \
        wh[kl][1] = rk[row + 64];                                             \
    }                                                                         \
    int f0 = 2 * p, f1 = 2 * p + 1, f2 = (p < 2) ? 16 + p : 0;                \
    {                                                                         \
        int r0 = f0 * 384 + hw * 128 + lane;                                  \
        int r1 = f1 * 384 + hw * 128 + lane;                                  \
        int r2 = f2 * 384 + hw * 128 + lane;                                  \
        wk1[0][0] = ker[r0];  wk1[0][1] = ker[r0 + 64];                       \
        wk1[1][0] = ker[r1];  wk1[1][1] = ker[r1 + 64];                       \
        wk1[2][0] = (p < 2) ? ker[r2] : 0.0f;                                 \
        wk1[2][1] = (p < 2) ? ker[r2 + 64] : 0.0f;                            \
    }                                                                         \
    int g0 = w, g1 = (w < 2) ? 16 + w : 0;                                    \
    {                                                                         \
        int r0 = g0 * 384 + 256 + lane;                                       \
        int r1 = g1 * 384 + 256 + lane;                                       \
        wk2[0][0] = ker[r0];  wk2[0][1] = ker[r0 + 64];                       \
        wk2[1][0] = (w < 2) ? ker[r1] : 0.0f;                                 \
        wk2[1][1] = (w < 2) ? ker[r1 + 64] : 0.0f;                            \
    }                                                                         \
    float ubias = bias[128 + 8 * w + ((lane & 31) >> 2)];                     \
    float fbz   = (tid < 512) ? bias[tid >> 2] : 0.0f;                        \
    float fbh   = (tid < 512) ? bias[256 + (tid >> 2)] : 0.0f;

#define DECLARE_IDX                                                           \
    const int tid  = threadIdx.x;                                             \
    const int w    = tid >> 6;                                                \
    const int lane = tid & 63;                                                \
    const int p    = w >> 1;                                                  \
    const int hw   = w & 1;

#define DECLARE_LDS                                                           \
    __shared__ __align__(16) float hldsf[512];                                \
    __shared__ __align__(16) float p1f[8 * 1024];   /* 32 KB stage1 */        \
    __shared__ __align__(16) float p2f[16 * 512];   /* 32 KB stage2 */

// ---------------------------------------------------------------------------
// K2: 250 wgs x 1024 threads; 4 chains/wg; t = 0..198
// ---------------------------------------------------------------------------
__global__ __launch_bounds__(1024, 1)
__attribute__((amdgpu_waves_per_eu(4, 4)))
void k_scan(const float* __restrict__ in,  const float* __restrict__ ker,
            const float* __restrict__ rk,  const float* __restrict__ bias,
            const float* __restrict__ sh0, const int* __restrict__ win,
            float* __restrict__ sfinal)
{
    DECLARE_IDX
    const int bx = blockIdx.x;
    DECLARE_LDS
    LOAD_WEIGHTS

    if (tid < 512)
        hldsf[tid] = sh0[(bx * 4 + (tid & 3)) * Uz + (tid >> 2)];

    const int4* winp = (const int4*)win;               // [Tz][NWG]
    int4 wv_cur = winp[bx];
    int4 wv_nxt = winp[NWG + bx];

    auto ldx = [&](int4 wv, int t, int jb) -> float {
        if (lane >= 36) return 0.0f;
        int j = lane / 18, f = lane - j * 18;
        int jj = jb + j;
        int b = (jj == 0) ? wv.x : (jj == 1) ? wv.y : (jj == 2) ? wv.z : wv.w;
        if (b < 0) return 0.0f;
        return in[((size_t)b * Tz + t) * Fz + f];
    };
    float xa = ldx(wv_cur, 0, 0), xb = ldx(wv_cur, 0, 2);
    __syncthreads();

    for (int t = 0; t < Tz - 1; ++t) {
        int tf = (t + 2 < Tz) ? t + 2 : Tz - 1;
        int4  wv_fut = winp[tf * NWG + bx];
        float xaN = ldx(wv_nxt, t + 1, 0);             // prefetch x(t+1)
        float xbN = ldx(wv_nxt, t + 1, 2);

        gstep<true>(tid, w, p, hw, lane, wzr, wh, wk1, wk2,
                    f0, f1, f2, g0, g1, ubias, fbz, fbh,
                    hldsf, p1f, p2f, xa, xb, wv_cur);

        xa = xaN; xb = xbN; wv_cur = wv_nxt; wv_nxt = wv_fut;
    }

    if (tid < 512) sfinal[bx * 512 + tid] = hldsf[tid];
}

// ---------------------------------------------------------------------------
// K3: final step t=199 for all 4096 rows + fused MLP head
// 256 wgs x 1024 threads, 4 iterations of 4 rows
// ---------------------------------------------------------------------------
__global__ __launch_bounds__(1024, 1)
__attribute__((amdgpu_waves_per_eu(4, 4)))
void k_final(const float* __restrict__ in,  const float* __restrict__ ker,
             const float* __restrict__ rk,  const float* __restrict__ bias,
             const float* __restrict__ sfinal,
             const float* __restrict__ w1,  const float* __restrict__ b1,
             const float* __restrict__ w2,  const float* __restrict__ b2,
             float* __restrict__ out)
{
    DECLARE_IDX
    DECLARE_LDS
    LOAD_WEIGHTS

    for (int it = 0; it < 4; ++it) {
        int bbase = blockIdx.x * 16 + it * 4;

        if (tid < 512) {   // gather h = sfinal[id]; chain j = tid&3, col c = tid>>2
            int j  = tid & 3, c = tid >> 2;
            int id = (int)in[((size_t)(bbase + j) * Tz + (Tz - 1)) * Fz];
            id = min(max(id, 0), NIDS - 1);
            hldsf[tid] = sfinal[(id >> 2) * 512 + c * 4 + (id & 3)];
        }
        float xa = 0.0f, xb = 0.0f;
        if (lane < 36) {
            int j = lane / 18, f = lane - j * 18;
            xa = in[((size_t)(bbase + j)     * Tz + (Tz - 1)) * Fz + f];
            xb = in[((size_t)(bbase + 2 + j) * Tz + (Tz - 1)) * Fz + f];
        }
        __syncthreads();

        gstep<false>(tid, w, p, hw, lane, wzr, wh, wk1, wk2,
                     f0, f1, f2, g0, g1, ubias, fbz, fbh,
                     hldsf, p1f, p2f, xa, xb, make_int4(0, 0, 0, 0));

        // MLP head: wave j = tid>>6 (<4) handles row j; lane = hidden unit
        if (tid < 256) {
            int j  = tid >> 6, un = tid & 63;
            float dacc = b1[un];
#pragma unroll
            for (int k = 0; k < Uz; ++k)
                dacc = fmaf(hldsf[k * 4 + j], w1[k * 64 + un], dacc);
            float v = fmaxf(dacc, 0.0f) * w2[un];
#pragma unroll
            for (int off = 32; off > 0; off >>= 1) v += __shfl_xor(v, off, 64);
            if (un == 0)
                out[bbase + j] = 1.0f / (1.0f + expf(-(v + b2[0])));
        }
        __syncthreads();
    }
}

// ---------------------------------------------------------------------------
extern "C" void kernel_launch(void* const* d_in, const int* in_sizes, int n_in,
                              void* d_out, int out_size, void* d_ws, size_t ws_size,
                              hipStream_t stream) {
    const float* in   = (const float*)d_in[0];
    const float* ker  = (const float*)d_in[1];
    const float* rk   = (const float*)d_in[2];
    const float* bias = (const float*)d_in[3];
    const float* sh0  = (const float*)d_in[4];
    const float* w1   = (const float*)d_in[5];
    const float* b1   = (const float*)d_in[6];
    const float* w2   = (const float*)d_in[7];
    const float* b2   = (const float*)d_in[8];
    float* out = (float*)d_out;

    int*   win    = (int*)d_ws;                                          // [Tz][NIDS]
    float* sfinal = (float*)((char*)d_ws + (size_t)Tz * NIDS * sizeof(int));

    hipMemsetAsync(win, 0xFF, (size_t)Tz * NIDS * sizeof(int), stream);  // -1

    hipLaunchKernelGGL(k_winner, dim3((Bz * Tz + 255) / 256), dim3(256), 0, stream,
                       in, win);
    hipLaunchKernelGGL(k_scan, dim3(NWG), dim3(1024), 0, stream,
                       in, ker, rk, bias, sh0, win, sfinal);
    hipLaunchKernelGGL(k_final, dim3(Bz / 16), dim3(1024), 0, stream,
                       in, ker, rk, bias, sfinal, w1, b1, w2, b2, out);
}

// Round 7
// 1557.015 us; speedup vs baseline: 1.3655x; 1.0344x over previous
//
#include <hip/hip_runtime.h>
#include <math.h>

#define Bz   4096
#define Tz   200
#define Fz   18
#define Uz   128
#define NIDS 1000
#define NWG  250   // NIDS/4

__device__ __forceinline__ float hsig(float x) {
    return fminf(fmaxf(fmaf(x, 0.2f, 0.5f), 0.0f), 1.0f);
}
__device__ __forceinline__ float rlane(float v, int l) {
    return __int_as_float(__builtin_amdgcn_readlane(__float_as_int(v), l));
}

// ---------------------------------------------------------------------------
// K1: winner per (t,id): win[t*NIDS+id] = max{b : ids[b,t]==id}  (last-wins)
// ---------------------------------------------------------------------------
__global__ void k_winner(const float* __restrict__ in, int* __restrict__ win) {
    int idx = blockIdx.x * blockDim.x + threadIdx.x;
    if (idx >= Bz * Tz) return;
    int b = idx / Tz, t = idx - b * Tz;
    int id = (int)in[(size_t)idx * Fz];
    id = min(max(id, 0), NIDS - 1);
    atomicMax(&win[t * NIDS + id], b);
}

// ---------------------------------------------------------------------------
// One GRU step, 1024 threads = 16 waves, 4 chains, 3 barriers.
// stage1 (256 cols): wave-pair p=w>>1 owns k in [16p,16p+16); half hw=w&1
//   covers cols {hw*128+lane, +64}. Partials -> p1f[8][256][4] (32 KB).
// u-reduce: wave w reduces its OWN 8 r-cols (no barrier needed after),
//   u kept in registers (lane uq*4+uj holds u[8w+uq][chain uj]).
// stage2 (128 cols): wave w owns k in [8w,8w+8); cols {lane, lane+64}.
//   Partials -> p2f (front 32 KB of a 48 KB buffer; the tail is
//   intentional padding so LDS/wg = 82 KB > 80 KB -> only 1 wg/CU fits ->
//   backend must budget VGPRs for 4 waves/EU = 128 regs -> no spill).
// finish (tid<512): z-reduce from p1f + p-reduce from p2f -> h_new.
// ---------------------------------------------------------------------------
template<bool MASK>
__device__ __forceinline__ void gstep(
    int tid, int w, int p, int hw, int lane,
    const float (&wzr)[16][2], const float (&wh)[8][2],
    const float (&wk1)[3][2], const float (&wk2)[2][2],
    int f0, int f1, int f2, int g0, int g1,
    float ubias, float fbz, float fbh,
    float* hldsf, float* p1f, float* p2f,
    float xa, float xb, int4 act)
{
    const int l15 = lane & 15;
    const int l31 = lane & 31;

    // ---- stage 1: partials of [x@K + h@Rzr] over (k-slice 16, col-half) ----
    float4 hd4 = ((const float4*)hldsf)[p * 16 + l15];
    float hdj[4] = {hd4.x, hd4.y, hd4.z, hd4.w};
    float az[2][4];
#pragma unroll
    for (int j = 0; j < 4; ++j) { az[0][j] = 0.f; az[1][j] = 0.f; }

#pragma unroll
    for (int j = 0; j < 4; ++j) {
        float src = (j < 2) ? xa : xb;
        int base = (j & 1) * 18;
        float xv0 = rlane(src, base + f0);
        float xv1 = rlane(src, base + f1);
        float xv2 = rlane(src, base + f2);
        az[0][j] = fmaf(xv0, wk1[0][0], az[0][j]);
        az[1][j] = fmaf(xv0, wk1[0][1], az[1][j]);
        az[0][j] = fmaf(xv1, wk1[1][0], az[0][j]);
        az[1][j] = fmaf(xv1, wk1[1][1], az[1][j]);
        az[0][j] = fmaf(xv2, wk1[2][0], az[0][j]);
        az[1][j] = fmaf(xv2, wk1[2][1], az[1][j]);
    }
#pragma unroll
    for (int kl = 0; kl < 16; ++kl) {
#pragma unroll
        for (int j = 0; j < 4; ++j) {
            float hv = rlane(hdj[j], kl);
            az[0][j] = fmaf(hv, wzr[kl][0], az[0][j]);
            az[1][j] = fmaf(hv, wzr[kl][1], az[1][j]);
        }
    }
    ((float4*)p1f)[p * 256 + hw * 128 + lane]      = make_float4(az[0][0], az[0][1], az[0][2], az[0][3]);
    ((float4*)p1f)[p * 256 + hw * 128 + lane + 64] = make_float4(az[1][0], az[1][1], az[1][2], az[1][3]);
    __syncthreads();                                   // A

    // ---- wave-local u-reduce: u[8w+uq][uj] into lane l31 = uq*4+uj ----
    float ureg;
    {
        int uq = l31 >> 2, uj = l31 & 3;
        int ucol = 128 + 8 * w + uq;
        float us = ubias;
#pragma unroll
        for (int pp = 0; pp < 8; ++pp) us += p1f[pp * 1024 + ucol * 4 + uj];
        ureg = hsig(us) * hldsf[(8 * w + uq) * 4 + uj];
    }

    // ---- stage 2: partials of [x@K2 + u@Rh] over (k-slice 8, M=2 cols) ----
    float pa[2][4];
#pragma unroll
    for (int j = 0; j < 4; ++j) { pa[0][j] = 0.f; pa[1][j] = 0.f; }
#pragma unroll
    for (int j = 0; j < 4; ++j) {
        float src = (j < 2) ? xa : xb;
        int base = (j & 1) * 18;
        float xv0 = rlane(src, base + g0);
        float xv1 = rlane(src, base + g1);
        pa[0][j] = fmaf(xv0, wk2[0][0], pa[0][j]);
        pa[1][j] = fmaf(xv0, wk2[0][1], pa[1][j]);
        pa[0][j] = fmaf(xv1, wk2[1][0], pa[0][j]);
        pa[1][j] = fmaf(xv1, wk2[1][1], pa[1][j]);
    }
#pragma unroll
    for (int kl = 0; kl < 8; ++kl) {
#pragma unroll
        for (int j = 0; j < 4; ++j) {
            float uv = rlane(ureg, kl * 4 + j);
            pa[0][j] = fmaf(uv, wh[kl][0], pa[0][j]);
            pa[1][j] = fmaf(uv, wh[kl][1], pa[1][j]);
        }
    }
    ((float4*)p2f)[w * 128 + lane]      = make_float4(pa[0][0], pa[0][1], pa[0][2], pa[0][3]);
    ((float4*)p2f)[w * 128 + lane + 64] = make_float4(pa[1][0], pa[1][1], pa[1][2], pa[1][3]);
    __syncthreads();                                   // C

    // ---- finish (tid < 512): z-reduce + p-reduce -> h_new -> hlds ----
    if (tid < 512) {
        float zs = fbz;
#pragma unroll
        for (int pp = 0; pp < 8; ++pp) zs += p1f[pp * 1024 + tid];
        float z = hsig(zs);
        float ps = fbh;
#pragma unroll
        for (int ww = 0; ww < 16; ++ww) ps += p2f[ww * 512 + tid];
        float hh = tanhf(ps);
        float ho = hldsf[tid];
        float hn = fmaf(z, ho - hh, hh);
        if (MASK) {
            int j = tid & 3;
            int av = (j == 0) ? act.x : (j == 1) ? act.y : (j == 2) ? act.z : act.w;
            if (av < 0) hn = ho;
        }
        hldsf[tid] = hn;
    }
    __syncthreads();                                   // D
}

// ---------------------------------------------------------------------------
// weight preload (58 floats/thread) + bias regs, shared by both kernels
// ---------------------------------------------------------------------------
#define LOAD_WEIGHTS                                                          \
    float wzr[16][2], wh[8][2], wk1[3][2], wk2[2][2];                         \
    _Pragma("unroll")                                                         \
    for (int kl = 0; kl < 16; ++kl) {                                         \
        int row = (p * 16 + kl) * 384 + hw * 128 + lane;                      \
        wzr[kl][0] = rk[row];                                                 \
        wzr[kl][1] = rk[row + 64];                                            \
    }                                                                         \
    _Pragma("unroll")                                                         \
    for (int kl = 0; kl < 8; ++kl) {                                          \
        int row = (w * 8 + kl) * 384 + 256 + lane;                            \
        wh[kl][0] = rk[row];                                                  \
        wh[kl][1] = rk[row + 64];                                             \
    }                                                                         \
    int f0 = 2 * p, f1 = 2 * p + 1, f2 = (p < 2) ? 16 + p : 0;                \
    {                                                                         \
        int r0 = f0 * 384 + hw * 128 + lane;                                  \
        int r1 = f1 * 384 + hw * 128 + lane;                                  \
        int r2 = f2 * 384 + hw * 128 + lane;                                  \
        wk1[0][0] = ker[r0];  wk1[0][1] = ker[r0 + 64];                       \
        wk1[1][0] = ker[r1];  wk1[1][1] = ker[r1 + 64];                       \
        wk1[2][0] = (p < 2) ? ker[r2] : 0.0f;                                 \
        wk1[2][1] = (p < 2) ? ker[r2 + 64] : 0.0f;                            \
    }                                                                         \
    int g0 = w, g1 = (w < 2) ? 16 + w : 0;                                    \
    {                                                                         \
        int r0 = g0 * 384 + 256 + lane;                                       \
        int r1 = g1 * 384 + 256 + lane;                                       \
        wk2[0][0] = ker[r0];  wk2[0][1] = ker[r0 + 64];                       \
        wk2[1][0] = (w < 2) ? ker[r1] : 0.0f;                                 \
        wk2[1][1] = (w < 2) ? ker[r1 + 64] : 0.0f;                            \
    }                                                                         \
    float ubias = bias[128 + 8 * w + ((lane & 31) >> 2)];                     \
    float fbz   = (tid < 512) ? bias[tid >> 2] : 0.0f;                        \
    float fbh   = (tid < 512) ? bias[256 + (tid >> 2)] : 0.0f;

#define DECLARE_IDX                                                           \
    const int tid  = threadIdx.x;                                             \
    const int w    = tid >> 6;                                                \
    const int lane = tid & 63;                                                \
    const int p    = w >> 1;                                                  \
    const int hw   = w & 1;

// p2f: used region = 8192 floats (32 KB); tail 4096 floats (16 KB) is
// deliberate padding. Total LDS = 2 KB + 32 KB + 48 KB = 82 KB > 80 KB
// -> only ONE workgroup fits a CU's 160 KB LDS -> the register allocator's
// occupancy target drops to 16 waves/CU (4 waves/EU) -> 128-VGPR budget.
#define DECLARE_LDS                                                           \
    __shared__ __align__(16) float hldsf[512];                                \
    __shared__ __align__(16) float p1f[8 * 1024];                             \
    __shared__ __align__(16) float p2f[8 * 1024 + 4096];

// ---------------------------------------------------------------------------
// K2: 250 wgs x 1024 threads; 4 chains/wg; t = 0..198
// ---------------------------------------------------------------------------
__global__ __launch_bounds__(1024)
__attribute__((amdgpu_waves_per_eu(4, 4)))
void k_scan(const float* __restrict__ in,  const float* __restrict__ ker,
            const float* __restrict__ rk,  const float* __restrict__ bias,
            const float* __restrict__ sh0, const int* __restrict__ win,
            float* __restrict__ sfinal)
{
    DECLARE_IDX
    const int bx = blockIdx.x;
    DECLARE_LDS
    LOAD_WEIGHTS

    if (tid < 512)
        hldsf[tid] = sh0[(bx * 4 + (tid & 3)) * Uz + (tid >> 2)];

    const int4* winp = (const int4*)win;               // [Tz][NWG]
    int4 wv_cur = winp[bx];
    int4 wv_nxt = winp[NWG + bx];

    auto ldx = [&](int4 wv, int t, int jb) -> float {
        if (lane >= 36) return 0.0f;
        int j = lane / 18, f = lane - j * 18;
        int jj = jb + j;
        int b = (jj == 0) ? wv.x : (jj == 1) ? wv.y : (jj == 2) ? wv.z : wv.w;
        if (b < 0) return 0.0f;
        return in[((size_t)b * Tz + t) * Fz + f];
    };
    float xa = ldx(wv_cur, 0, 0), xb = ldx(wv_cur, 0, 2);
    __syncthreads();

    for (int t = 0; t < Tz - 1; ++t) {
        int tf = (t + 2 < Tz) ? t + 2 : Tz - 1;
        int4  wv_fut = winp[tf * NWG + bx];
        float xaN = ldx(wv_nxt, t + 1, 0);             // prefetch x(t+1)
        float xbN = ldx(wv_nxt, t + 1, 2);

        gstep<true>(tid, w, p, hw, lane, wzr, wh, wk1, wk2,
                    f0, f1, f2, g0, g1, ubias, fbz, fbh,
                    hldsf, p1f, p2f, xa, xb, wv_cur);

        xa = xaN; xb = xbN; wv_cur = wv_nxt; wv_nxt = wv_fut;
    }

    if (tid < 512) sfinal[bx * 512 + tid] = hldsf[tid];
}

// ---------------------------------------------------------------------------
// K3: final step t=199 for all 4096 rows + fused MLP head
// 256 wgs x 1024 threads, 4 iterations of 4 rows
// ---------------------------------------------------------------------------
__global__ __launch_bounds__(1024)
__attribute__((amdgpu_waves_per_eu(4, 4)))
void k_final(const float* __restrict__ in,  const float* __restrict__ ker,
             const float* __restrict__ rk,  const float* __restrict__ bias,
             const float* __restrict__ sfinal,
             const float* __restrict__ w1,  const float* __restrict__ b1,
             const float* __restrict__ w2,  const float* __restrict__ b2,
             float* __restrict__ out)
{
    DECLARE_IDX
    DECLARE_LDS
    LOAD_WEIGHTS

    for (int it = 0; it < 4; ++it) {
        int bbase = blockIdx.x * 16 + it * 4;

        if (tid < 512) {   // gather h = sfinal[id]; chain j = tid&3, col c = tid>>2
            int j  = tid & 3, c = tid >> 2;
            int id = (int)in[((size_t)(bbase + j) * Tz + (Tz - 1)) * Fz];
            id = min(max(id, 0), NIDS - 1);
            hldsf[tid] = sfinal[(id >> 2) * 512 + c * 4 + (id & 3)];
        }
        float xa = 0.0f, xb = 0.0f;
        if (lane < 36) {
            int j = lane / 18, f = lane - j * 18;
            xa = in[((size_t)(bbase + j)     * Tz + (Tz - 1)) * Fz + f];
            xb = in[((size_t)(bbase + 2 + j) * Tz + (Tz - 1)) * Fz + f];
        }
        __syncthreads();

        gstep<false>(tid, w, p, hw, lane, wzr, wh, wk1, wk2,
                     f0, f1, f2, g0, g1, ubias, fbz, fbh,
                     hldsf, p1f, p2f, xa, xb, make_int4(0, 0, 0, 0));

        // MLP head: wave j = tid>>6 (<4) handles row j; lane = hidden unit
        if (tid < 256) {
            int j  = tid >> 6, un = tid & 63;
            float dacc = b1[un];
#pragma unroll
            for (int k = 0; k < Uz; ++k)
                dacc = fmaf(hldsf[k * 4 + j], w1[k * 64 + un], dacc);
            float v = fmaxf(dacc, 0.0f) * w2[un];
#pragma unroll
            for (int off = 32; off > 0; off >>= 1) v += __shfl_xor(v, off, 64);
            if (un == 0)
                out[bbase + j] = 1.0f / (1.0f + expf(-(v + b2[0])));
        }
        __syncthreads();
    }
}

// ---------------------------------------------------------------------------
extern "C" void kernel_launch(void* const* d_in, const int* in_sizes, int n_in,
                              void* d_out, int out_size, void* d_ws, size_t ws_size,
                              hipStream_t stream) {
    const float* in   = (const float*)d_in[0];
    const float* ker  = (const float*)d_in[1];
    const float* rk   = (const float*)d_in[2];
    const float* bias = (const float*)d_in[3];
    const float* sh0  = (const float*)d_in[4];
    const float* w1   = (const float*)d_in[5];
    const float* b1   = (const float*)d_in[6];
    const float* w2   = (const float*)d_in[7];
    const float* b2   = (const float*)d_in[8];
    float* out = (float*)d_out;

    int*   win    = (int*)d_ws;                                          // [Tz][NIDS]
    float* sfinal = (float*)((char*)d_ws + (size_t)Tz * NIDS * sizeof(int));

    hipMemsetAsync(win, 0xFF, (size_t)Tz * NIDS * sizeof(int), stream);  // -1

    hipLaunchKernelGGL(k_winner, dim3((Bz * Tz + 255) / 256), dim3(256), 0, stream,
                       in, win);
    hipLaunchKernelGGL(k_scan, dim3(NWG), dim3(1024), 0, stream,
                       in, ker, rk, bias, sh0, win, sfinal);
    hipLaunchKernelGGL(k_final, dim3(Bz / 16), dim3(1024), 0, stream,
                       in, ker, rk, bias, sfinal, w1, b1, w2, b2, out);
}

// Round 8
// 1006.461 us; speedup vs baseline: 2.1124x; 1.5470x over previous
//
#include <hip/hip_runtime.h>
#include <math.h>

#define Bz   4096
#define Tz   200
#define Fz   18
#define Uz   128
#define NIDS 1000
#define NWG  250   // NIDS/4

__device__ __forceinline__ float hsig(float x) {
    return fminf(fmaxf(fmaf(x, 0.2f, 0.5f), 0.0f), 1.0f);
}
__device__ __forceinline__ float rlane(float v, int l) {
    return __int_as_float(__builtin_amdgcn_readlane(__float_as_int(v), l));
}

// ---------------------------------------------------------------------------
// K1: winner per (t,id): win[t*NIDS+id] = max{b : ids[b,t]==id}  (last-wins)
// ---------------------------------------------------------------------------
__global__ void k_winner(const float* __restrict__ in, int* __restrict__ win) {
    int idx = blockIdx.x * blockDim.x + threadIdx.x;
    if (idx >= Bz * Tz) return;
    int b = idx / Tz, t = idx - b * Tz;
    int id = (int)in[(size_t)idx * Fz];
    id = min(max(id, 0), NIDS - 1);
    atomicMax(&win[t * NIDS + id], b);
}

// ---------------------------------------------------------------------------
// One GRU step. 512 threads = 8 waves, 4 chains, 3 barriers.
// Wave w owns k-slice [16w, 16w+16). Lower 8 k's: weights in REGISTERS.
// Upper 8 k's: weights STREAMED from global rk each step (coalesced b32,
// L2-resident, vmem pipe co-issues with VALU — replaces compiler spill).
// stage1: lane covers 4 cols {lane,+64,+128,+192} of 256. az[4][4].
// u-reduce: wave-local, lane uq*4+uj owns u[16w+uq][chain uj] (in reg).
// stage2: lane covers 2 cols {lane,+64} of 128. pa[2][4].
// Partials: p1f[8][4][256], p2f[8][4][128] — [slice][j][col] orientation
// makes writes bank=lane%32 (2-way, free) and reads <=4-way.
// finish: all 512 threads, (c,j) = (tid>>2, tid&3) -> h_new -> hlds.
// ---------------------------------------------------------------------------
template<bool MASK>
__device__ __forceinline__ void gstep(
    int tid, int w, int lane,
    const float (&wzr)[8][4], const float (&whr)[8][2],
    const float (&wk1)[3][4], const float (&wk2)[3][2],
    const float* __restrict__ gw1, const float* __restrict__ gw2,
    int f0, int f1, int f2,
    float ubias, float fbz, float fbh,
    float* hldsf, float* p1f, float* p2f,
    float xa, float xb, int4 act)
{
    const int l15 = lane & 15;

    // ---- streamed upper-half weights: issue early, consume late ----
    float ta[16], tb[16];
#pragma unroll
    for (int s = 0; s < 16; ++s)
        ta[s] = gw1[(s >> 2) * 384 + 64 * (s & 3)];          // rows kl8=0..3
#pragma unroll
    for (int s = 0; s < 16; ++s)
        tb[s] = gw1[((s >> 2) + 4) * 384 + 64 * (s & 3)];    // rows kl8=4..7

    // ---- stage 1: az[c][j] partials of [x@K + h@Rzr] ----
    float4 hd4 = ((const float4*)hldsf)[w * 16 + l15];
    float hdj[4] = {hd4.x, hd4.y, hd4.z, hd4.w};
    float az[4][4];
#pragma unroll
    for (int i = 0; i < 4; ++i)
#pragma unroll
        for (int j = 0; j < 4; ++j) az[i][j] = 0.0f;

#pragma unroll
    for (int j = 0; j < 4; ++j) {
        float src = (j < 2) ? xa : xb;
        int base = (j & 1) * 18;
        float xv0 = rlane(src, base + f0);
        float xv1 = rlane(src, base + f1);
        float xv2 = rlane(src, base + f2);
#pragma unroll
        for (int i = 0; i < 4; ++i) {
            az[i][j] = fmaf(xv0, wk1[0][i], az[i][j]);
            az[i][j] = fmaf(xv1, wk1[1][i], az[i][j]);
            az[i][j] = fmaf(xv2, wk1[2][i], az[i][j]);
        }
    }
#pragma unroll
    for (int kl = 0; kl < 8; ++kl)
#pragma unroll
        for (int j = 0; j < 4; ++j) {
            float hv = rlane(hdj[j], kl);
#pragma unroll
            for (int i = 0; i < 4; ++i) az[i][j] = fmaf(hv, wzr[kl][i], az[i][j]);
        }
#pragma unroll
    for (int kl8 = 0; kl8 < 4; ++kl8)
#pragma unroll
        for (int j = 0; j < 4; ++j) {
            float hv = rlane(hdj[j], 8 + kl8);
#pragma unroll
            for (int i = 0; i < 4; ++i) az[i][j] = fmaf(hv, ta[kl8 * 4 + i], az[i][j]);
        }
#pragma unroll
    for (int kl8 = 0; kl8 < 4; ++kl8)
#pragma unroll
        for (int j = 0; j < 4; ++j) {
            float hv = rlane(hdj[j], 12 + kl8);
#pragma unroll
            for (int i = 0; i < 4; ++i) az[i][j] = fmaf(hv, tb[kl8 * 4 + i], az[i][j]);
        }
#pragma unroll
    for (int i = 0; i < 4; ++i)
#pragma unroll
        for (int j = 0; j < 4; ++j)
            p1f[w * 1024 + j * 256 + lane + 64 * i] = az[i][j];
    __syncthreads();                                   // A

    // ---- wave-local u-reduce: lane uq*4+uj -> u[16w+uq][uj] ----
    const int uq = lane >> 2, uj = lane & 3;
    float us = ubias;
#pragma unroll
    for (int pp = 0; pp < 8; ++pp)
        us += p1f[pp * 1024 + uj * 256 + 128 + 16 * w + uq];
    float ureg = hsig(us) * hldsf[(16 * w + uq) * 4 + uj];

    // ---- stage 2: pa[c][j] partials of [x@K2 + u@Rh] ----
    float tc[16];
#pragma unroll
    for (int s = 0; s < 16; ++s)
        tc[s] = gw2[(s >> 1) * 384 + 64 * (s & 1)];          // rows kl8=0..7, 2 cols
    float pa[2][4];
#pragma unroll
    for (int i = 0; i < 2; ++i)
#pragma unroll
        for (int j = 0; j < 4; ++j) pa[i][j] = 0.0f;

#pragma unroll
    for (int j = 0; j < 4; ++j) {
        float src = (j < 2) ? xa : xb;
        int base = (j & 1) * 18;
        float xv0 = rlane(src, base + f0);
        float xv1 = rlane(src, base + f1);
        float xv2 = rlane(src, base + f2);
#pragma unroll
        for (int i = 0; i < 2; ++i) {
            pa[i][j] = fmaf(xv0, wk2[0][i], pa[i][j]);
            pa[i][j] = fmaf(xv1, wk2[1][i], pa[i][j]);
            pa[i][j] = fmaf(xv2, wk2[2][i], pa[i][j]);
        }
    }
#pragma unroll
    for (int kl = 0; kl < 8; ++kl)
#pragma unroll
        for (int j = 0; j < 4; ++j) {
            float uv = rlane(ureg, kl * 4 + j);
#pragma unroll
            for (int i = 0; i < 2; ++i) pa[i][j] = fmaf(uv, whr[kl][i], pa[i][j]);
        }
#pragma unroll
    for (int kl8 = 0; kl8 < 8; ++kl8)
#pragma unroll
        for (int j = 0; j < 4; ++j) {
            float uv = rlane(ureg, (8 + kl8) * 4 + j);
#pragma unroll
            for (int i = 0; i < 2; ++i) pa[i][j] = fmaf(uv, tc[kl8 * 2 + i], pa[i][j]);
        }
#pragma unroll
    for (int i = 0; i < 2; ++i)
#pragma unroll
        for (int j = 0; j < 4; ++j)
            p2f[w * 512 + j * 128 + lane + 64 * i] = pa[i][j];
    __syncthreads();                                   // C

    // ---- finish: all threads, (c,j) = (tid>>2, tid&3) ----
    {
        const int c = tid >> 2, j = tid & 3;
        float zs = fbz;
#pragma unroll
        for (int pp = 0; pp < 8; ++pp) zs += p1f[pp * 1024 + j * 256 + c];
        float z = hsig(zs);
        float ps = fbh;
#pragma unroll
        for (int ww = 0; ww < 8; ++ww) ps += p2f[ww * 512 + j * 128 + c];
        float hh = tanhf(ps);
        float ho = hldsf[tid];
        float hn = fmaf(z, ho - hh, hh);
        if (MASK) {
            int av = (j == 0) ? act.x : (j == 1) ? act.y : (j == 2) ? act.z : act.w;
            if (av < 0) hn = ho;
        }
        hldsf[tid] = hn;
    }
    __syncthreads();                                   // D
}

// ---------------------------------------------------------------------------
// weight preload: 66 floats in regs (lower k-halves + x-weights) + global
// stream pointers for the upper halves. Shared by both kernels.
// ---------------------------------------------------------------------------
#define LOAD_WEIGHTS                                                          \
    float wzr[8][4], whr[8][2], wk1[3][4], wk2[3][2];                         \
    _Pragma("unroll")                                                         \
    for (int kl = 0; kl < 8; ++kl) {                                          \
        int row = (16 * w + kl) * 384;                                        \
        _Pragma("unroll")                                                     \
        for (int i = 0; i < 4; ++i) wzr[kl][i] = rk[row + lane + 64 * i];     \
        _Pragma("unroll")                                                     \
        for (int i = 0; i < 2; ++i) whr[kl][i] = rk[row + 256 + lane + 64*i]; \
    }                                                                         \
    const int f0 = 2 * w, f1 = 2 * w + 1, f2 = (w < 2) ? 16 + w : 0;          \
    _Pragma("unroll")                                                         \
    for (int i = 0; i < 4; ++i) {                                             \
        wk1[0][i] = ker[f0 * 384 + lane + 64 * i];                            \
        wk1[1][i] = ker[f1 * 384 + lane + 64 * i];                            \
        wk1[2][i] = (w < 2) ? ker[f2 * 384 + lane + 64 * i] : 0.0f;           \
    }                                                                         \
    _Pragma("unroll")                                                         \
    for (int i = 0; i < 2; ++i) {                                             \
        wk2[0][i] = ker[f0 * 384 + 256 + lane + 64 * i];                      \
        wk2[1][i] = ker[f1 * 384 + 256 + lane + 64 * i];                      \
        wk2[2][i] = (w < 2) ? ker[f2 * 384 + 256 + lane + 64 * i] : 0.0f;     \
    }                                                                         \
    const float* gw1 = rk + (16 * w + 8) * 384 + lane;                        \
    const float* gw2 = gw1 + 256;                                             \
    float ubias = bias[128 + 16 * w + (lane >> 2)];                           \
    float fbz   = bias[tid >> 2];                                             \
    float fbh   = bias[256 + (tid >> 2)];

#define DECLARE_LDS                                                           \
    __shared__ __align__(16) float hldsf[512];                                \
    __shared__ __align__(16) float p1f[8 * 1024];   /* [p][j][256] 32 KB */   \
    __shared__ __align__(16) float p2f[8 * 512];    /* [w][j][128] 16 KB */

// ---------------------------------------------------------------------------
// K2: 250 wgs x 512 threads; 4 chains/wg; t = 0..198
// ---------------------------------------------------------------------------
__global__ __launch_bounds__(512)
void k_scan(const float* __restrict__ in,  const float* __restrict__ ker,
            const float* __restrict__ rk,  const float* __restrict__ bias,
            const float* __restrict__ sh0, const int* __restrict__ win,
            float* __restrict__ sfinal)
{
    const int tid  = threadIdx.x;
    const int w    = tid >> 6;
    const int lane = tid & 63;
    const int bx   = blockIdx.x;
    DECLARE_LDS
    LOAD_WEIGHTS

    hldsf[tid] = sh0[(bx * 4 + (tid & 3)) * Uz + (tid >> 2)];

    const int4* winp = (const int4*)win;               // [Tz][NWG]
    int4 wv_cur = winp[bx];
    int4 wv_nxt = winp[NWG + bx];

    auto ldx = [&](int4 wv, int t, int jb) -> float {
        if (lane >= 36) return 0.0f;
        int j = lane / 18, f = lane - j * 18;
        int jj = jb + j;
        int b = (jj == 0) ? wv.x : (jj == 1) ? wv.y : (jj == 2) ? wv.z : wv.w;
        if (b < 0) return 0.0f;
        return in[((size_t)b * Tz + t) * Fz + f];
    };
    float xa = ldx(wv_cur, 0, 0), xb = ldx(wv_cur, 0, 2);
    __syncthreads();

    for (int t = 0; t < Tz - 1; ++t) {
        int tf = (t + 2 < Tz) ? t + 2 : Tz - 1;
        int4  wv_fut = winp[tf * NWG + bx];
        float xaN = ldx(wv_nxt, t + 1, 0);             // prefetch x(t+1)
        float xbN = ldx(wv_nxt, t + 1, 2);

        gstep<true>(tid, w, lane, wzr, whr, wk1, wk2, gw1, gw2,
                    f0, f1, f2, ubias, fbz, fbh,
                    hldsf, p1f, p2f, xa, xb, wv_cur);

        xa = xaN; xb = xbN; wv_cur = wv_nxt; wv_nxt = wv_fut;
    }

    sfinal[bx * 512 + tid] = hldsf[tid];
}

// ---------------------------------------------------------------------------
// K3: final step t=199 for all 4096 rows + fused MLP head
// 256 wgs x 512 threads, 4 iterations of 4 rows
// ---------------------------------------------------------------------------
__global__ __launch_bounds__(512)
void k_final(const float* __restrict__ in,  const float* __restrict__ ker,
             const float* __restrict__ rk,  const float* __restrict__ bias,
             const float* __restrict__ sfinal,
             const float* __restrict__ w1,  const float* __restrict__ b1,
             const float* __restrict__ w2,  const float* __restrict__ b2,
             float* __restrict__ out)
{
    const int tid  = threadIdx.x;
    const int w    = tid >> 6;
    const int lane = tid & 63;
    DECLARE_LDS
    LOAD_WEIGHTS

    for (int it = 0; it < 4; ++it) {
        int bbase = blockIdx.x * 16 + it * 4;

        {   // gather h = sfinal[id]; sfinal packed [wg][c][j]
            int j  = tid & 3, c = tid >> 2;
            int id = (int)in[((size_t)(bbase + j) * Tz + (Tz - 1)) * Fz];
            id = min(max(id, 0), NIDS - 1);
            hldsf[tid] = sfinal[(id >> 2) * 512 + c * 4 + (id & 3)];
        }
        float xa = 0.0f, xb = 0.0f;
        if (lane < 36) {
            int j = lane / 18, f = lane - j * 18;
            xa = in[((size_t)(bbase + j)     * Tz + (Tz - 1)) * Fz + f];
            xb = in[((size_t)(bbase + 2 + j) * Tz + (Tz - 1)) * Fz + f];
        }
        __syncthreads();

        gstep<false>(tid, w, lane, wzr, whr, wk1, wk2, gw1, gw2,
                     f0, f1, f2, ubias, fbz, fbh,
                     hldsf, p1f, p2f, xa, xb, make_int4(0, 0, 0, 0));

        // MLP head: wave j = tid>>6 (<4) handles row j; lane = hidden unit
        if (tid < 256) {
            int j  = tid >> 6, un = tid & 63;
            float dacc = b1[un];
#pragma unroll
            for (int k = 0; k < Uz; ++k)
                dacc = fmaf(hldsf[k * 4 + j], w1[k * 64 + un], dacc);
            float v = fmaxf(dacc, 0.0f) * w2[un];
#pragma unroll
            for (int off = 32; off > 0; off >>= 1) v += __shfl_xor(v, off, 64);
            if (un == 0)
                out[bbase + j] = 1.0f / (1.0f + expf(-(v + b2[0])));
        }
        __syncthreads();
    }
}

// ---------------------------------------------------------------------------
extern "C" void kernel_launch(void* const* d_in, const int* in_sizes, int n_in,
                              void* d_out, int out_size, void* d_ws, size_t ws_size,
                              hipStream_t stream) {
    const float* in   = (const float*)d_in[0];
    const float* ker  = (const float*)d_in[1];
    const float* rk   = (const float*)d_in[2];
    const float* bias = (const float*)d_in[3];
    const float* sh0  = (const float*)d_in[4];
    const float* w1   = (const float*)d_in[5];
    const float* b1   = (const float*)d_in[6];
    const float* w2   = (const float*)d_in[7];
    const float* b2   = (const float*)d_in[8];
    float* out = (float*)d_out;

    int*   win    = (int*)d_ws;                                          // [Tz][NIDS]
    float* sfinal = (float*)((char*)d_ws + (size_t)Tz * NIDS * sizeof(int));

    hipMemsetAsync(win, 0xFF, (size_t)Tz * NIDS * sizeof(int), stream);  // -1

    hipLaunchKernelGGL(k_winner, dim3((Bz * Tz + 255) / 256), dim3(256), 0, stream,
                       in, win);
    hipLaunchKernelGGL(k_scan, dim3(NWG), dim3(512), 0, stream,
                       in, ker, rk, bias, sh0, win, sfinal);
    hipLaunchKernelGGL(k_final, dim3(Bz / 16), dim3(512), 0, stream,
                       in, ker, rk, bias, sfinal, w1, b1, w2, b2, out);
}